// Round 12
// baseline (1182.907 us; speedup 1.0000x reference)
//
#include <hip/hip_runtime.h>
#include <hip/hip_bf16.h>
#include <type_traits>

// Problem constants
constexpr int CB = 16, CS = 512, CE = 256, CH = 8, CDK = 32;
constexpr int CNDYN = 6;
constexpr int CT = CB * CS;          // 8192 tokens
constexpr float SCALE = 0.17677669529663687f; // 1/sqrt(32)

typedef __bf16 bf16x8 __attribute__((ext_vector_type(8)));
typedef float f32x4 __attribute__((ext_vector_type(4)));
typedef unsigned short u16x8 __attribute__((ext_vector_type(8)));

__device__ __forceinline__ unsigned short f2bf(float x) {
    union { float f; unsigned u; } v; v.f = x;
    unsigned r = v.u + 0x7fff + ((v.u >> 16) & 1);   // RNE
    return (unsigned short)(r >> 16);
}

// ---------------------------------------------------------------- embeddings
__global__ __launch_bounds__(256) void embed_kernel(
    const int* __restrict__ skills, const int* __restrict__ responses,
    const int* __restrict__ questions,
    const float* __restrict__ q_embed, const float* __restrict__ qa_embed,
    const float* __restrict__ q_embed_diff, const float* __restrict__ qa_embed_diff,
    const float* __restrict__ difficult,
    float* __restrict__ q_emb, float* __restrict__ qa_emb, float* __restrict__ xb)
{
    int t = blockIdx.x;
    int e = threadIdx.x;
    int sk = skills[t];
    int r  = responses[t];
    r = (r > -1) ? r : 0;            // masked_r
    float pid = difficult[questions[t]];
    float qe  = q_embed[(size_t)sk * CE + e];
    float qd  = q_embed_diff[(size_t)sk * CE + e];
    float qv  = qe + pid * qd;
    float qae = qe + qa_embed[(size_t)r * CE + e];
    float qad = qa_embed_diff[((size_t)sk + 1000 * r) * CE + e];
    float qav = qae + pid * (qad + qd);
    q_emb[(size_t)t * CE + e]  = qv;
    xb[(size_t)t * CE + e]     = qv;
    qa_emb[(size_t)t * CE + e] = qav;
}

// ---------------------------------------------------------------- weight prep
__device__ __forceinline__ void transpose_tile(
    const float* __restrict__ src, unsigned short* __restrict__ dst, int K, int N)
{
    __shared__ unsigned short T[64][72];
    int k0 = blockIdx.y * 64, n0 = blockIdx.x * 64;
    int t = threadIdx.x;
    int kr = t >> 3, nsg = (t & 7) * 8;
#pragma unroll
    for (int rr = 0; rr < 64; rr += 32) {
        const float* p = src + (size_t)(k0 + kr + rr) * N + n0 + nsg;
        float4 a = *reinterpret_cast<const float4*>(p);
        float4 b = *reinterpret_cast<const float4*>(p + 4);
        int k = kr + rr;
        T[nsg + 0][k] = f2bf(a.x); T[nsg + 1][k] = f2bf(a.y);
        T[nsg + 2][k] = f2bf(a.z); T[nsg + 3][k] = f2bf(a.w);
        T[nsg + 4][k] = f2bf(b.x); T[nsg + 5][k] = f2bf(b.y);
        T[nsg + 6][k] = f2bf(b.z); T[nsg + 7][k] = f2bf(b.w);
    }
    __syncthreads();
    {
        int n = t >> 2, ks = (t & 3) * 16;
        unsigned short* dp = dst + (size_t)(n0 + n) * K + k0 + ks;
        *reinterpret_cast<u16x8*>(dp)     = *reinterpret_cast<const u16x8*>(&T[n][ks]);
        *reinterpret_cast<u16x8*>(dp + 8) = *reinterpret_cast<const u16x8*>(&T[n][ks + 8]);
    }
}

// grid (4,4,60): z -> {Wq,Wv,Wo,fW1,fW2}[z/12], layer z%12 (256x256 each).
__global__ __launch_bounds__(256) void prep_w_layers(
    const float* __restrict__ Wq, const float* __restrict__ Wv,
    const float* __restrict__ Wo, const float* __restrict__ W1,
    const float* __restrict__ W2,
    unsigned short* __restrict__ qvT, unsigned short* __restrict__ woT,
    unsigned short* __restrict__ w1T, unsigned short* __restrict__ w2T)
{
    int z = blockIdx.z;
    int which = z / 12, l = z % 12;
    const float* src;
    unsigned short* dst;
    if      (which == 0) { src = Wq + (size_t)l * 65536; dst = qvT + (size_t)l * 131072; }
    else if (which == 1) { src = Wv + (size_t)l * 65536; dst = qvT + (size_t)l * 131072 + 65536; }
    else if (which == 2) { src = Wo + (size_t)l * 65536; dst = woT + (size_t)l * 65536; }
    else if (which == 3) { src = W1 + (size_t)l * 65536; dst = w1T + (size_t)l * 65536; }
    else                 { src = W2 + (size_t)l * 65536; dst = w2T + (size_t)l * 65536; }
    transpose_tile(src, dst, 256, 256);
}

__global__ __launch_bounds__(256) void prep_w_one(
    const float* __restrict__ src, unsigned short* __restrict__ dst, int K, int N)
{
    transpose_tile(src, dst, K, N);
}

// ---------------------------------------------------------------- MFMA GEMM
// C = A[M,K] @ W + bias; W as WT[N][K] bf16. A: fp32 (convert) or bf16 (copy).
// C: fp32 or bf16.  64x64 tile, BK=64, 4 waves. split>0: cols>=split -> C2.
template <typename TA, typename TC>
__global__ __launch_bounds__(256) void gemm_mfma(
    const TA* __restrict__ A, const unsigned short* __restrict__ WT,
    const float* __restrict__ bias, TC* __restrict__ C,
    const float* __restrict__ bias2, TC* __restrict__ C2,
    int M, int N, int K, int relu, int split)
{
    __shared__ __attribute__((aligned(16))) unsigned short As[64][72];
    __shared__ __attribute__((aligned(16))) unsigned short Bs[64][72];
    int tid = threadIdx.x;
    int bm = blockIdx.y * 64, bn = blockIdx.x * 64;
    int w = tid >> 6, lane = tid & 63;
    int wr = w >> 1, wc = w & 1;
    int lo = lane & 15, hi = lane >> 4;
    int srow = tid >> 2, sseg = (tid & 3) * 16;
    f32x4 acc[2][2] = {};

    for (int kk = 0; kk < K; kk += 64) {
        if constexpr (std::is_same<TA, float>::value) {
            const float* ap = A + (size_t)(bm + srow) * K + kk + sseg;
            float4 a0 = *reinterpret_cast<const float4*>(ap);
            float4 a1 = *reinterpret_cast<const float4*>(ap + 4);
            float4 a2 = *reinterpret_cast<const float4*>(ap + 8);
            float4 a3 = *reinterpret_cast<const float4*>(ap + 12);
            u16x8 p0, p1;
            p0[0]=f2bf(a0.x); p0[1]=f2bf(a0.y); p0[2]=f2bf(a0.z); p0[3]=f2bf(a0.w);
            p0[4]=f2bf(a1.x); p0[5]=f2bf(a1.y); p0[6]=f2bf(a1.z); p0[7]=f2bf(a1.w);
            p1[0]=f2bf(a2.x); p1[1]=f2bf(a2.y); p1[2]=f2bf(a2.z); p1[3]=f2bf(a2.w);
            p1[4]=f2bf(a3.x); p1[5]=f2bf(a3.y); p1[6]=f2bf(a3.z); p1[7]=f2bf(a3.w);
            *reinterpret_cast<u16x8*>(&As[srow][sseg])     = p0;
            *reinterpret_cast<u16x8*>(&As[srow][sseg + 8]) = p1;
        } else {
            const unsigned short* ap = A + (size_t)(bm + srow) * K + kk + sseg;
            *reinterpret_cast<u16x8*>(&As[srow][sseg])     = *reinterpret_cast<const u16x8*>(ap);
            *reinterpret_cast<u16x8*>(&As[srow][sseg + 8]) = *reinterpret_cast<const u16x8*>(ap + 8);
        }
        {
            const unsigned short* bp = WT + (size_t)(bn + srow) * K + kk + sseg;
            *reinterpret_cast<u16x8*>(&Bs[srow][sseg])     = *reinterpret_cast<const u16x8*>(bp);
            *reinterpret_cast<u16x8*>(&Bs[srow][sseg + 8]) = *reinterpret_cast<const u16x8*>(bp + 8);
        }
        __syncthreads();
#pragma unroll
        for (int ks = 0; ks < 2; ++ks) {
            bf16x8 a0 = *reinterpret_cast<const bf16x8*>(&As[wr * 32 + lo][ks * 32 + hi * 8]);
            bf16x8 a1 = *reinterpret_cast<const bf16x8*>(&As[wr * 32 + 16 + lo][ks * 32 + hi * 8]);
            bf16x8 b0 = *reinterpret_cast<const bf16x8*>(&Bs[wc * 32 + lo][ks * 32 + hi * 8]);
            bf16x8 b1 = *reinterpret_cast<const bf16x8*>(&Bs[wc * 32 + 16 + lo][ks * 32 + hi * 8]);
            acc[0][0] = __builtin_amdgcn_mfma_f32_16x16x32_bf16(a0, b0, acc[0][0], 0, 0, 0);
            acc[0][1] = __builtin_amdgcn_mfma_f32_16x16x32_bf16(a0, b1, acc[0][1], 0, 0, 0);
            acc[1][0] = __builtin_amdgcn_mfma_f32_16x16x32_bf16(a1, b0, acc[1][0], 0, 0, 0);
            acc[1][1] = __builtin_amdgcn_mfma_f32_16x16x32_bf16(a1, b1, acc[1][1], 0, 0, 0);
        }
        __syncthreads();
    }
    const float* bp = bias;
    TC* Cp = C;
    int ldc = split ? split : N;
    int cb = bn;
    if (split && bn >= split) { bp = bias2; Cp = C2; ldc = N - split; cb = bn - split; }
#pragma unroll
    for (int i = 0; i < 2; ++i)
#pragma unroll
        for (int j = 0; j < 2; ++j) {
            int col = cb + wc * 32 + j * 16 + lo;
            float bv = bp[col];
#pragma unroll
            for (int r = 0; r < 4; ++r) {
                int row = bm + wr * 32 + i * 16 + hi * 4 + r;
                float v = acc[i][j][r] + bv;
                if (relu) v = fmaxf(v, 0.f);
                if constexpr (std::is_same<TC, float>::value)
                    Cp[(size_t)row * ldc + col] = v;
                else
                    Cp[(size_t)row * ldc + col] = f2bf(v);
            }
        }
}

// ---------------------------------------------------------------- attention
// Persistent-KV bf16 MFMA flash.  Q,V,Ctx all bf16 [B*S][E].  K == Q (kq_same).
// Grid: (b,h,half) = 256 blocks x 512 threads (8 waves). Stage all 512 keys
// once; each wave computes 2 query-groups with no block barriers in the loop.
// Router head-mask applied at ctx writeout. strict row 0 -> uniform (s=0).
__global__ __launch_bounds__(512) void attn_mfma(
    const unsigned short* __restrict__ Q, const unsigned short* __restrict__ V,
    unsigned short* __restrict__ Ctx, const unsigned char* __restrict__ gm,
    int strict)
{
    __shared__ __attribute__((aligned(16))) unsigned short Ks[512][40];     // 40 KB
    __shared__ __attribute__((aligned(16))) unsigned short VTc[8][32][72];  // 36 KB
    __shared__ __attribute__((aligned(16))) unsigned short Ps[8][16][72];   // 18 KB (also f32 ctxbuf[16][36])

    int blk = blockIdx.x;
    int half = blk & 1;
    int h = (blk >> 1) & 7;
    int b = blk >> 4;
    int tid = threadIdx.x;
    int w = tid >> 6, lane = tid & 63;
    int lo = lane & 15, hi = lane >> 4;

    // ---- stage all of K (=Q) and V^T (once) ----
#pragma unroll
    for (int r = 0; r < 4; ++r) {
        int row = (tid >> 2) + r * 128;
        int d0 = (tid & 3) * 8;
        u16x8 kv = *reinterpret_cast<const u16x8*>(Q + ((size_t)b * CS + row) * CE + h * 32 + d0);
        *reinterpret_cast<u16x8*>(&Ks[row][d0]) = kv;
        u16x8 vv = *reinterpret_cast<const u16x8*>(V + ((size_t)b * CS + row) * CE + h * 32 + d0);
        int c8 = row >> 6, kc = row & 63;
        VTc[c8][d0+0][kc]=vv[0]; VTc[c8][d0+1][kc]=vv[1];
        VTc[c8][d0+2][kc]=vv[2]; VTc[c8][d0+3][kc]=vv[3];
        VTc[c8][d0+4][kc]=vv[4]; VTc[c8][d0+5][kc]=vv[5];
        VTc[c8][d0+6][kc]=vv[6]; VTc[c8][d0+7][kc]=vv[7];
    }
    __syncthreads();

    for (int it = 0; it < 2; ++it) {
        int gg = half * 16 + w + it * 8;     // global query group 0..31
        int qg0 = gg * 16;
        int qg = qg0 + lo;                   // this lane's query row
        bool uni = strict && (qg == 0);
        bf16x8 qfrag = *reinterpret_cast<const bf16x8*>(&Ks[qg0 + lo][hi * 8]);

        f32x4 ctx0 = {0.f,0.f,0.f,0.f}, ctx1 = {0.f,0.f,0.f,0.f};
        float m = -1e30f, l = 0.f;
        int nch = (strict && qg0 == 0) ? 8 : ((gg >> 2) + 1);

        for (int c = 0; c < nch; ++c) {
            f32x4 sacc[4];
#pragma unroll
            for (int kt = 0; kt < 4; ++kt) {
                bf16x8 kfrag = *reinterpret_cast<const bf16x8*>(&Ks[c * 64 + kt * 16 + lo][hi * 8]);
                f32x4 z = {0.f,0.f,0.f,0.f};
                sacc[kt] = __builtin_amdgcn_mfma_f32_16x16x32_bf16(kfrag, qfrag, z, 0, 0, 0);
            }
            float sv[16];
            float mt = -1e30f;
#pragma unroll
            for (int kt = 0; kt < 4; ++kt)
#pragma unroll
                for (int r = 0; r < 4; ++r) {
                    int kidx = c * 64 + kt * 16 + hi * 4 + r;
                    float s = sacc[kt][r] * SCALE;
                    bool valid = strict ? (kidx < qg) : (kidx <= qg);
                    s = valid ? s : -1e30f;
                    if (uni) s = 0.f;
                    sv[kt * 4 + r] = s;
                    mt = fmaxf(mt, s);
                }
            mt = fmaxf(mt, __shfl_xor(mt, 16));
            mt = fmaxf(mt, __shfl_xor(mt, 32));
            float mn = fmaxf(m, mt);
            float co = __expf(m - mn);
            float lt = 0.f;
#pragma unroll
            for (int i = 0; i < 16; ++i) {
                float p = __expf(sv[i] - mn);
                sv[i] = p;
                lt += p;
            }
            lt += __shfl_xor(lt, 16);
            lt += __shfl_xor(lt, 32);
            l = l * co + lt;
            m = mn;
#pragma unroll
            for (int r = 0; r < 4; ++r) { ctx0[r] *= co; ctx1[r] *= co; }
#pragma unroll
            for (int kt = 0; kt < 4; ++kt) {
                unsigned short* pd = &Ps[w][lo][kt * 16 + hi * 4];
                pd[0] = f2bf(sv[kt * 4 + 0]); pd[1] = f2bf(sv[kt * 4 + 1]);
                pd[2] = f2bf(sv[kt * 4 + 2]); pd[3] = f2bf(sv[kt * 4 + 3]);
            }
            // wave-local ordering: P writes (cross-lane) -> P reads
            asm volatile("s_waitcnt lgkmcnt(0)" ::: "memory");
            __builtin_amdgcn_sched_barrier(0);
#pragma unroll
            for (int kh = 0; kh < 2; ++kh) {
                bf16x8 pfrag = *reinterpret_cast<const bf16x8*>(&Ps[w][lo][kh * 32 + hi * 8]);
                bf16x8 v0 = *reinterpret_cast<const bf16x8*>(&VTc[c][lo][kh * 32 + hi * 8]);
                bf16x8 v1 = *reinterpret_cast<const bf16x8*>(&VTc[c][16 + lo][kh * 32 + hi * 8]);
                ctx0 = __builtin_amdgcn_mfma_f32_16x16x32_bf16(v0, pfrag, ctx0, 0, 0, 0);
                ctx1 = __builtin_amdgcn_mfma_f32_16x16x32_bf16(v1, pfrag, ctx1, 0, 0, 0);
            }
        }

        // ---- normalize + writeout (mask applied) via per-wave LDS transpose ----
        float inv = 1.f / l;
        float* cb = reinterpret_cast<float*>(&Ps[w][0][0]);   // [16 q][36 d]
#pragma unroll
        for (int r = 0; r < 4; ++r) {
            cb[lo * 36 + (hi * 4 + r)]      = ctx0[r] * inv;
            cb[lo * 36 + (16 + hi * 4 + r)] = ctx1[r] * inv;
        }
        asm volatile("s_waitcnt lgkmcnt(0)" ::: "memory");
        __builtin_amdgcn_sched_barrier(0);
        {
            int qloc = lane >> 2, d0 = (lane & 3) * 8;
            const float* src = cb + qloc * 36 + d0;
            int i = qg0 + qloc;
            float mf = ((gm[(size_t)b * CS + i] >> h) & 1) ? 1.f : 0.f;
            u16x8 o;
#pragma unroll
            for (int k = 0; k < 8; ++k) o[k] = f2bf(src[k] * mf);
            *reinterpret_cast<u16x8*>(Ctx + ((size_t)b * CS + i) * CE + h * 32 + d0) = o;
        }
        asm volatile("s_waitcnt lgkmcnt(0)" ::: "memory");   // cb reads done before next it's P writes
        __builtin_amdgcn_sched_barrier(0);
    }
}

// ---------------------------------------------------------------- router gate mask
// Wave per token (8 waves/block): logits = q_in @ Wg; top-4 -> 8-bit head mask.
__global__ __launch_bounds__(512) void gate_mask(
    const float* __restrict__ qin, const float* __restrict__ Wg,
    unsigned char* __restrict__ mb)
{
    int w = threadIdx.x >> 6, lane = threadIdx.x & 63;
    int t = blockIdx.x * 8 + w;
    const float* q = qin + (size_t)t * CE;
    float p[CNDYN] = {};
#pragma unroll
    for (int r = 0; r < 4; ++r) {
        int e = lane + r * 64;
        float qe = q[e];
        const float* wg = &Wg[(size_t)e * CNDYN];
#pragma unroll
        for (int j = 0; j < CNDYN; ++j) p[j] += qe * wg[j];
    }
#pragma unroll
    for (int o = 32; o > 0; o >>= 1)
#pragma unroll
        for (int j = 0; j < CNDYN; ++j) p[j] += __shfl_down(p[j], o);
    if (lane == 0) {
        int mask = 3;
        for (int j = 0; j < CNDYN; ++j) {
            int rank = 0;
            for (int k = 0; k < CNDYN; ++k)
                if (p[k] > p[j] || (p[k] == p[j] && k < j)) rank++;
            if (rank < 4) mask |= 1 << (2 + j);
        }
        mb[t] = (unsigned char)mask;
    }
}

// ---------------------------------------------------------------- residual+LN
__global__ __launch_bounds__(256) void add_ln(
    const float* __restrict__ A, const float* __restrict__ Bv,
    const float* __restrict__ g, const float* __restrict__ bb,
    float* __restrict__ O)
{
    int w = threadIdx.x >> 6, lane = threadIdx.x & 63;
    int t = blockIdx.x * 4 + w;
    size_t base = (size_t)t * CE + lane * 4;
    float4 a = *reinterpret_cast<const float4*>(A + base);
    float4 b = *reinterpret_cast<const float4*>(Bv + base);
    float4 v = {a.x + b.x, a.y + b.y, a.z + b.z, a.w + b.w};
    float s = v.x + v.y + v.z + v.w;
#pragma unroll
    for (int o = 32; o > 0; o >>= 1) s += __shfl_xor(s, o);
    float mean = s * (1.f / CE);
    float4 d = {v.x - mean, v.y - mean, v.z - mean, v.w - mean};
    float s2 = d.x * d.x + d.y * d.y + d.z * d.z + d.w * d.w;
#pragma unroll
    for (int o = 32; o > 0; o >>= 1) s2 += __shfl_xor(s2, o);
    float rstd = rsqrtf(s2 * (1.f / CE) + 1e-5f);
    float4 gg = *reinterpret_cast<const float4*>(g + lane * 4);
    float4 bv4 = *reinterpret_cast<const float4*>(bb + lane * 4);
    float4 o4 = {d.x * rstd * gg.x + bv4.x, d.y * rstd * gg.y + bv4.y,
                 d.z * rstd * gg.z + bv4.z, d.w * rstd * gg.w + bv4.w};
    *reinterpret_cast<float4*>(O + base) = o4;
}

// ---------------------------------------------------------------- concat (bf16 out)
__global__ __launch_bounds__(256) void concat_kernel(
    const float* __restrict__ x, const float* __restrict__ qe,
    unsigned short* __restrict__ cat)
{
    int t = blockIdx.x, e = threadIdx.x;
    int o = e * 2;
    float2 v;
    if (o < 256) v = *reinterpret_cast<const float2*>(&x[(size_t)t * CE + o]);
    else         v = *reinterpret_cast<const float2*>(&qe[(size_t)t * CE + o - 256]);
    unsigned pk = (unsigned)f2bf(v.x) | ((unsigned)f2bf(v.y) << 16);
    *reinterpret_cast<unsigned*>(&cat[(size_t)t * 512 + o]) = pk;
}

// ---------------------------------------------------------------- final dot + sigmoid
__global__ __launch_bounds__(64) void final_kernel(
    const float* __restrict__ H2, const float* __restrict__ W3,
    const float* __restrict__ b3, float* __restrict__ out)
{
    int t = blockIdx.x, lane = threadIdx.x;
    const float* h = H2 + (size_t)t * CE;
    float s = 0.f;
#pragma unroll
    for (int r = 0; r < 4; ++r) {
        int e = lane + r * 64;
        s += h[e] * W3[e];
    }
#pragma unroll
    for (int o = 32; o > 0; o >>= 1) s += __shfl_down(s, o);
    if (lane == 0) {
        float v = 1.f / (1.f + __expf(-(s + b3[0])));
        int b = t >> 9, si = t & 511;
        if (si > 0) out[(size_t)b * (CS - 1) + si - 1] = v;
    }
}

// ---------------------------------------------------------------- driver
extern "C" void kernel_launch(void* const* d_in, const int* in_sizes, int n_in,
                              void* d_out, int out_size, void* d_ws, size_t ws_size,
                              hipStream_t stream)
{
    const int* skills    = (const int*)d_in[0];
    const int* responses = (const int*)d_in[1];
    const int* questions = (const int*)d_in[2];
    const float* q_embed       = (const float*)d_in[4];
    const float* qa_embed      = (const float*)d_in[5];
    const float* q_embed_diff  = (const float*)d_in[6];
    const float* qa_embed_diff = (const float*)d_in[7];
    const float* difficult     = (const float*)d_in[8];
    const float* Wq = (const float*)d_in[9];  const float* bq = (const float*)d_in[10];
    const float* Wv = (const float*)d_in[11]; const float* bv = (const float*)d_in[12];
    const float* Wo = (const float*)d_in[13]; const float* bo = (const float*)d_in[14];
    const float* Wg = (const float*)d_in[15];
    const float* ln1g = (const float*)d_in[16]; const float* ln1b = (const float*)d_in[17];
    const float* ln2g = (const float*)d_in[18]; const float* ln2b = (const float*)d_in[19];
    const float* fW1 = (const float*)d_in[20]; const float* fb1 = (const float*)d_in[21];
    const float* fW2 = (const float*)d_in[22]; const float* fb2 = (const float*)d_in[23];
    const float* oW1 = (const float*)d_in[24]; const float* ob1 = (const float*)d_in[25];
    const float* oW2 = (const float*)d_in[26]; const float* ob2 = (const float*)d_in[27];
    const float* oW3 = (const float*)d_in[28]; const float* ob3 = (const float*)d_in[29];
    float* out = (float*)d_out;

    char* ws = (char*)d_ws;
    const size_t R = (size_t)CT * CE * sizeof(float);   // 8 MB per region
    float* q_emb = (float*)(ws + 0 * R);
    float* xb    = (float*)(ws + 1 * R);                // also final H2 (f32)
    float* yb    = (float*)(ws + 2 * R);
    float* S0f   = (float*)(ws + 3 * R);                // f32 GEMM outs / bf16 Q / bf16 cat
    float* S1f   = (float*)(ws + 4 * R);                // f32 LN out / bf16 V
    float* S2f   = (float*)(ws + 5 * R);                // bf16 ctx / bf16 H1
    unsigned short* S0b = (unsigned short*)S0f;
    unsigned short* S1b = (unsigned short*)S1f;
    unsigned short* S2b = (unsigned short*)S2f;
    unsigned short* qvT = (unsigned short*)(ws + 7 * R);  // [12][512][256]
    unsigned short* woT = qvT + (size_t)12 * 131072;      // [12][256][256]
    unsigned short* w1T = woT + (size_t)12 * 65536;
    unsigned short* w2T = w1T + (size_t)12 * 65536;
    unsigned short* o1T = w2T + (size_t)12 * 65536;       // [512][512]
    unsigned short* o2T = o1T + (size_t)512 * 512;        // [256][512]
    unsigned char* maskbuf = (unsigned char*)(o2T + (size_t)256 * 512);
    (void)in_sizes; (void)n_in; (void)out_size; (void)ws_size;

    // weight conversion (every call; graph-safe)
    prep_w_layers<<<dim3(4, 4, 60), 256, 0, stream>>>(Wq, Wv, Wo, fW1, fW2, qvT, woT, w1T, w2T);
    prep_w_one<<<dim3(8, 8), 256, 0, stream>>>(oW1, o1T, 512, 512);
    prep_w_one<<<dim3(4, 8), 256, 0, stream>>>(oW2, o2T, 512, 256);

    embed_kernel<<<CT, 256, 0, stream>>>(skills, responses, questions,
        q_embed, qa_embed, q_embed_diff, qa_embed_diff, difficult, q_emb, yb, xb);

    auto layer = [&](int li, const float* qin, const float* vin, float* outc, int strict) {
        if (qin == vin) {   // fused Q+V projection (N=512, split at 256) -> bf16
            gemm_mfma<float, unsigned short><<<dim3(8, 128), 256, 0, stream>>>(
                qin, qvT + (size_t)li * 131072, bq + (size_t)li * CE, S0b,
                bv + (size_t)li * CE, S1b, CT, 512, CE, 0, 256);
        } else {
            gemm_mfma<float, unsigned short><<<dim3(4, 128), 256, 0, stream>>>(
                qin, qvT + (size_t)li * 131072, bq + (size_t)li * CE, S0b,
                nullptr, nullptr, CT, CE, CE, 0, 0);
            gemm_mfma<float, unsigned short><<<dim3(4, 128), 256, 0, stream>>>(
                vin, qvT + (size_t)li * 131072 + 65536, bv + (size_t)li * CE, S1b,
                nullptr, nullptr, CT, CE, CE, 0, 0);
        }
        gate_mask<<<CT / 8, 512, 0, stream>>>(qin, Wg + (size_t)li * CE * CNDYN, maskbuf);
        attn_mfma<<<CB * CH * 2, 512, 0, stream>>>(S0b, S1b, S2b, maskbuf, strict);
        gemm_mfma<unsigned short, float><<<dim3(4, 128), 256, 0, stream>>>(
            S2b, woT + (size_t)li * 65536, bo + (size_t)li * CE, S0f,
            nullptr, nullptr, CT, CE, CE, 0, 0);
        add_ln<<<CT / 4, 256, 0, stream>>>(qin, S0f, ln1g + (size_t)li * CE, ln1b + (size_t)li * CE, S1f);
        gemm_mfma<float, unsigned short><<<dim3(4, 128), 256, 0, stream>>>(
            S1f, w1T + (size_t)li * 65536, fb1 + (size_t)li * CE, S2b,
            nullptr, nullptr, CT, CE, CE, 1, 0);
        gemm_mfma<unsigned short, float><<<dim3(4, 128), 256, 0, stream>>>(
            S2b, w2T + (size_t)li * 65536, fb2 + (size_t)li * CE, S0f,
            nullptr, nullptr, CT, CE, CE, 0, 0);
        add_ln<<<CT / 4, 256, 0, stream>>>(S1f, S0f, ln2g + (size_t)li * CE, ln2b + (size_t)li * CE, outc);
    };

    for (int i = 0; i < 4; ++i) layer(i, yb, yb, yb, 0);
    int li = 4;
    for (int r = 0; r < 4; ++r) {
        layer(li, xb, xb, xb, 0); li++;
        layer(li, xb, yb, xb, 1); li++;   // q=x, k=x, v=y, strict mask
    }

    // output MLP: cat(bf16) -> H1(bf16, relu) -> H2(f32, relu) -> sigmoid dot
    concat_kernel<<<CT, 256, 0, stream>>>(xb, q_emb, S0b);
    gemm_mfma<unsigned short, unsigned short><<<dim3(8, 128), 256, 0, stream>>>(
        S0b, o1T, ob1, S2b, nullptr, nullptr, CT, 512, 512, 1, 0);
    gemm_mfma<unsigned short, float><<<dim3(4, 128), 256, 0, stream>>>(
        S2b, o2T, ob2, xb, nullptr, nullptr, CT, 256, 512, 1, 0);
    final_kernel<<<CT, 64, 0, stream>>>(xb, oW3, ob3, out);
}

// Round 13
// 1071.900 us; speedup vs baseline: 1.1036x; 1.1036x over previous
//
#include <hip/hip_runtime.h>
#include <hip/hip_bf16.h>
#include <type_traits>

// Problem constants
constexpr int CB = 16, CS = 512, CE = 256, CH = 8, CDK = 32;
constexpr int CNDYN = 6;
constexpr int CT = CB * CS;          // 8192 tokens
constexpr float SCALE = 0.17677669529663687f; // 1/sqrt(32)

typedef __bf16 bf16x8 __attribute__((ext_vector_type(8)));
typedef float f32x4 __attribute__((ext_vector_type(4)));
typedef unsigned short u16x8 __attribute__((ext_vector_type(8)));

__device__ __forceinline__ unsigned short f2bf(float x) {
    union { float f; unsigned u; } v; v.f = x;
    unsigned r = v.u + 0x7fff + ((v.u >> 16) & 1);   // RNE
    return (unsigned short)(r >> 16);
}

// ---------------------------------------------------------------- embeddings
__global__ __launch_bounds__(256) void embed_kernel(
    const int* __restrict__ skills, const int* __restrict__ responses,
    const int* __restrict__ questions,
    const float* __restrict__ q_embed, const float* __restrict__ qa_embed,
    const float* __restrict__ q_embed_diff, const float* __restrict__ qa_embed_diff,
    const float* __restrict__ difficult,
    float* __restrict__ q_emb, float* __restrict__ qa_emb, float* __restrict__ xb)
{
    int t = blockIdx.x;
    int e = threadIdx.x;
    int sk = skills[t];
    int r  = responses[t];
    r = (r > -1) ? r : 0;            // masked_r
    float pid = difficult[questions[t]];
    float qe  = q_embed[(size_t)sk * CE + e];
    float qd  = q_embed_diff[(size_t)sk * CE + e];
    float qv  = qe + pid * qd;
    float qae = qe + qa_embed[(size_t)r * CE + e];
    float qad = qa_embed_diff[((size_t)sk + 1000 * r) * CE + e];
    float qav = qae + pid * (qad + qd);
    q_emb[(size_t)t * CE + e]  = qv;
    xb[(size_t)t * CE + e]     = qv;
    qa_emb[(size_t)t * CE + e] = qav;
}

// ---------------------------------------------------------------- weight prep
__device__ __forceinline__ void transpose_tile(
    const float* __restrict__ src, unsigned short* __restrict__ dst, int K, int N)
{
    __shared__ unsigned short T[64][72];
    int k0 = blockIdx.y * 64, n0 = blockIdx.x * 64;
    int t = threadIdx.x;
    int kr = t >> 3, nsg = (t & 7) * 8;
#pragma unroll
    for (int rr = 0; rr < 64; rr += 32) {
        const float* p = src + (size_t)(k0 + kr + rr) * N + n0 + nsg;
        float4 a = *reinterpret_cast<const float4*>(p);
        float4 b = *reinterpret_cast<const float4*>(p + 4);
        int k = kr + rr;
        T[nsg + 0][k] = f2bf(a.x); T[nsg + 1][k] = f2bf(a.y);
        T[nsg + 2][k] = f2bf(a.z); T[nsg + 3][k] = f2bf(a.w);
        T[nsg + 4][k] = f2bf(b.x); T[nsg + 5][k] = f2bf(b.y);
        T[nsg + 6][k] = f2bf(b.z); T[nsg + 7][k] = f2bf(b.w);
    }
    __syncthreads();
    {
        int n = t >> 2, ks = (t & 3) * 16;
        unsigned short* dp = dst + (size_t)(n0 + n) * K + k0 + ks;
        *reinterpret_cast<u16x8*>(dp)     = *reinterpret_cast<const u16x8*>(&T[n][ks]);
        *reinterpret_cast<u16x8*>(dp + 8) = *reinterpret_cast<const u16x8*>(&T[n][ks + 8]);
    }
}

// grid (4,4,60): z -> {Wq,Wv,Wo,fW1,fW2}[z/12], layer z%12 (256x256 each).
__global__ __launch_bounds__(256) void prep_w_layers(
    const float* __restrict__ Wq, const float* __restrict__ Wv,
    const float* __restrict__ Wo, const float* __restrict__ W1,
    const float* __restrict__ W2,
    unsigned short* __restrict__ qvT, unsigned short* __restrict__ woT,
    unsigned short* __restrict__ w1T, unsigned short* __restrict__ w2T)
{
    int z = blockIdx.z;
    int which = z / 12, l = z % 12;
    const float* src;
    unsigned short* dst;
    if      (which == 0) { src = Wq + (size_t)l * 65536; dst = qvT + (size_t)l * 131072; }
    else if (which == 1) { src = Wv + (size_t)l * 65536; dst = qvT + (size_t)l * 131072 + 65536; }
    else if (which == 2) { src = Wo + (size_t)l * 65536; dst = woT + (size_t)l * 65536; }
    else if (which == 3) { src = W1 + (size_t)l * 65536; dst = w1T + (size_t)l * 65536; }
    else                 { src = W2 + (size_t)l * 65536; dst = w2T + (size_t)l * 65536; }
    transpose_tile(src, dst, 256, 256);
}

__global__ __launch_bounds__(256) void prep_w_one(
    const float* __restrict__ src, unsigned short* __restrict__ dst, int K, int N)
{
    transpose_tile(src, dst, K, N);
}

// ---------------------------------------------------------------- MFMA GEMM
// C = A[M,K] @ W + bias; W as WT[N][K] bf16. A: fp32 (convert) or bf16 (copy).
// C: fp32 or bf16.  64x64 tile, BK=64, 4 waves. split>0: cols>=split -> C2.
template <typename TA, typename TC>
__global__ __launch_bounds__(256) void gemm_mfma(
    const TA* __restrict__ A, const unsigned short* __restrict__ WT,
    const float* __restrict__ bias, TC* __restrict__ C,
    const float* __restrict__ bias2, TC* __restrict__ C2,
    int M, int N, int K, int relu, int split)
{
    __shared__ __attribute__((aligned(16))) unsigned short As[64][72];
    __shared__ __attribute__((aligned(16))) unsigned short Bs[64][72];
    int tid = threadIdx.x;
    int bm = blockIdx.y * 64, bn = blockIdx.x * 64;
    int w = tid >> 6, lane = tid & 63;
    int wr = w >> 1, wc = w & 1;
    int lo = lane & 15, hi = lane >> 4;
    int srow = tid >> 2, sseg = (tid & 3) * 16;
    f32x4 acc[2][2] = {};

    for (int kk = 0; kk < K; kk += 64) {
        if constexpr (std::is_same<TA, float>::value) {
            const float* ap = A + (size_t)(bm + srow) * K + kk + sseg;
            float4 a0 = *reinterpret_cast<const float4*>(ap);
            float4 a1 = *reinterpret_cast<const float4*>(ap + 4);
            float4 a2 = *reinterpret_cast<const float4*>(ap + 8);
            float4 a3 = *reinterpret_cast<const float4*>(ap + 12);
            u16x8 p0, p1;
            p0[0]=f2bf(a0.x); p0[1]=f2bf(a0.y); p0[2]=f2bf(a0.z); p0[3]=f2bf(a0.w);
            p0[4]=f2bf(a1.x); p0[5]=f2bf(a1.y); p0[6]=f2bf(a1.z); p0[7]=f2bf(a1.w);
            p1[0]=f2bf(a2.x); p1[1]=f2bf(a2.y); p1[2]=f2bf(a2.z); p1[3]=f2bf(a2.w);
            p1[4]=f2bf(a3.x); p1[5]=f2bf(a3.y); p1[6]=f2bf(a3.z); p1[7]=f2bf(a3.w);
            *reinterpret_cast<u16x8*>(&As[srow][sseg])     = p0;
            *reinterpret_cast<u16x8*>(&As[srow][sseg + 8]) = p1;
        } else {
            const unsigned short* ap = A + (size_t)(bm + srow) * K + kk + sseg;
            *reinterpret_cast<u16x8*>(&As[srow][sseg])     = *reinterpret_cast<const u16x8*>(ap);
            *reinterpret_cast<u16x8*>(&As[srow][sseg + 8]) = *reinterpret_cast<const u16x8*>(ap + 8);
        }
        {
            const unsigned short* bp = WT + (size_t)(bn + srow) * K + kk + sseg;
            *reinterpret_cast<u16x8*>(&Bs[srow][sseg])     = *reinterpret_cast<const u16x8*>(bp);
            *reinterpret_cast<u16x8*>(&Bs[srow][sseg + 8]) = *reinterpret_cast<const u16x8*>(bp + 8);
        }
        __syncthreads();
#pragma unroll
        for (int ks = 0; ks < 2; ++ks) {
            bf16x8 a0 = *reinterpret_cast<const bf16x8*>(&As[wr * 32 + lo][ks * 32 + hi * 8]);
            bf16x8 a1 = *reinterpret_cast<const bf16x8*>(&As[wr * 32 + 16 + lo][ks * 32 + hi * 8]);
            bf16x8 b0 = *reinterpret_cast<const bf16x8*>(&Bs[wc * 32 + lo][ks * 32 + hi * 8]);
            bf16x8 b1 = *reinterpret_cast<const bf16x8*>(&Bs[wc * 32 + 16 + lo][ks * 32 + hi * 8]);
            acc[0][0] = __builtin_amdgcn_mfma_f32_16x16x32_bf16(a0, b0, acc[0][0], 0, 0, 0);
            acc[0][1] = __builtin_amdgcn_mfma_f32_16x16x32_bf16(a0, b1, acc[0][1], 0, 0, 0);
            acc[1][0] = __builtin_amdgcn_mfma_f32_16x16x32_bf16(a1, b0, acc[1][0], 0, 0, 0);
            acc[1][1] = __builtin_amdgcn_mfma_f32_16x16x32_bf16(a1, b1, acc[1][1], 0, 0, 0);
        }
        __syncthreads();
    }
    const float* bp = bias;
    TC* Cp = C;
    int ldc = split ? split : N;
    int cb = bn;
    if (split && bn >= split) { bp = bias2; Cp = C2; ldc = N - split; cb = bn - split; }
#pragma unroll
    for (int i = 0; i < 2; ++i)
#pragma unroll
        for (int j = 0; j < 2; ++j) {
            int col = cb + wc * 32 + j * 16 + lo;
            float bv = bp[col];
#pragma unroll
            for (int r = 0; r < 4; ++r) {
                int row = bm + wr * 32 + i * 16 + hi * 4 + r;
                float v = acc[i][j][r] + bv;
                if (relu) v = fmaxf(v, 0.f);
                if constexpr (std::is_same<TC, float>::value)
                    Cp[(size_t)row * ldc + col] = v;
                else
                    Cp[(size_t)row * ldc + col] = f2bf(v);
            }
        }
}

// ---------------------------------------------------------------- fused layer tail
// Block: 32 rows, 512 threads (8 waves: wr=w>>2 rows, wc=w&3 cols of 64).
// GEMM1: Abf(bf16)@WT1 + bias1 -> +res -> LN(g,b) -> xout (f32)
// DO_FFN: also x@WT2 + bias2, relu -> Hout (bf16).  All K=256, N=256.
template <int DO_FFN>
__global__ __launch_bounds__(512) void fused_tail(
    const unsigned short* __restrict__ Abf, const unsigned short* __restrict__ WT1,
    const float* __restrict__ bias1, const float* __restrict__ res,
    const float* __restrict__ g, const float* __restrict__ bvec,
    float* __restrict__ xout,
    const unsigned short* __restrict__ WT2, const float* __restrict__ bias2,
    unsigned short* __restrict__ Hout)
{
    __shared__ __attribute__((aligned(16))) unsigned short A_s[32][264];
    __shared__ __attribute__((aligned(16))) unsigned short Bs[256][72];
    __shared__ float res_s[32][260];
    __shared__ float bias_s[256], g_s[256], b_s[256];
    __shared__ float red_s[256];

    int tid = threadIdx.x;
    int brow = blockIdx.x * 32;
    int w = tid >> 6, lane = tid & 63;
    int wr = w >> 2, wc = w & 3;
    int lo = lane & 15, hi = lane >> 4;
    int rowb = wr * 16 + hi * 4;            // + rr

    // ---- stage A (bf16), res (f32), bias1, g, b ----
    {
        int row = tid >> 4, seg = (tid & 15) * 16;
        const unsigned short* ap = Abf + (size_t)(brow + row) * CE + seg;
        *reinterpret_cast<u16x8*>(&A_s[row][seg])     = *reinterpret_cast<const u16x8*>(ap);
        *reinterpret_cast<u16x8*>(&A_s[row][seg + 8]) = *reinterpret_cast<const u16x8*>(ap + 8);
        const float* rp = res + (size_t)(brow + row) * CE + seg;
#pragma unroll
        for (int q = 0; q < 4; ++q)
            *reinterpret_cast<float4*>(&res_s[row][seg + q * 4]) = *reinterpret_cast<const float4*>(rp + q * 4);
        if (tid < 256) { bias_s[tid] = bias1[tid]; b_s[tid] = bvec[tid]; }
        else           { g_s[tid - 256] = g[tid - 256]; }
    }

    // ---- GEMM1 ----
    f32x4 acc[4] = {};
    for (int kc = 0; kc < 4; ++kc) {
        int k0 = kc * 64;
        __syncthreads();
        {   // stage WT1[256][k0..k0+64]
            int n = tid >> 1, half = (tid & 1) * 32;
            const unsigned short* bp = WT1 + (size_t)n * CE + k0 + half;
#pragma unroll
            for (int q = 0; q < 4; ++q)
                *reinterpret_cast<u16x8*>(&Bs[n][half + q * 8]) = *reinterpret_cast<const u16x8*>(bp + q * 8);
        }
        __syncthreads();
#pragma unroll
        for (int sub = 0; sub < 2; ++sub) {
            bf16x8 a = *reinterpret_cast<const bf16x8*>(&A_s[wr * 16 + lo][k0 + sub * 32 + hi * 8]);
#pragma unroll
            for (int nt = 0; nt < 4; ++nt) {
                bf16x8 b = *reinterpret_cast<const bf16x8*>(&Bs[wc * 64 + nt * 16 + lo][sub * 32 + hi * 8]);
                acc[nt] = __builtin_amdgcn_mfma_f32_16x16x32_bf16(a, b, acc[nt], 0, 0, 0);
            }
        }
    }
    __syncthreads();

    // ---- bias + residual + LN ----
    float vv[4][4];
    float part[4] = {};
#pragma unroll
    for (int nt = 0; nt < 4; ++nt) {
        int col = wc * 64 + nt * 16 + lo;
        float bc = bias_s[col];
#pragma unroll
        for (int rr = 0; rr < 4; ++rr) {
            float v = acc[nt][rr] + bc + res_s[rowb + rr][col];
            vv[nt][rr] = v; part[rr] += v;
        }
    }
#pragma unroll
    for (int rr = 0; rr < 4; ++rr)
#pragma unroll
        for (int m = 1; m < 16; m <<= 1) part[rr] += __shfl_xor(part[rr], m);
    if (lo == 0) {
#pragma unroll
        for (int rr = 0; rr < 4; ++rr) red_s[(rowb + rr) * 4 + wc] = part[rr];
    }
    __syncthreads();
    float mean[4], sq[4] = {};
#pragma unroll
    for (int rr = 0; rr < 4; ++rr) {
        float4 q = *reinterpret_cast<const float4*>(&red_s[(rowb + rr) * 4]);
        mean[rr] = (q.x + q.y + q.z + q.w) * (1.f / 256.f);
    }
#pragma unroll
    for (int nt = 0; nt < 4; ++nt)
#pragma unroll
        for (int rr = 0; rr < 4; ++rr) { float d = vv[nt][rr] - mean[rr]; sq[rr] += d * d; }
#pragma unroll
    for (int rr = 0; rr < 4; ++rr)
#pragma unroll
        for (int m = 1; m < 16; m <<= 1) sq[rr] += __shfl_xor(sq[rr], m);
    if (lo == 0) {
#pragma unroll
        for (int rr = 0; rr < 4; ++rr) red_s[128 + (rowb + rr) * 4 + wc] = sq[rr];
    }
    __syncthreads();
    float rstd[4];
#pragma unroll
    for (int rr = 0; rr < 4; ++rr) {
        float4 q = *reinterpret_cast<const float4*>(&red_s[128 + (rowb + rr) * 4]);
        rstd[rr] = rsqrtf((q.x + q.y + q.z + q.w) * (1.f / 256.f) + 1e-5f);
    }
    // ---- write x (f32) and optionally keep bf16 in A_s for GEMM2 ----
#pragma unroll
    for (int nt = 0; nt < 4; ++nt) {
        int col = wc * 64 + nt * 16 + lo;
        float gc = g_s[col], bc = b_s[col];
#pragma unroll
        for (int rr = 0; rr < 4; ++rr) {
            float x = (vv[nt][rr] - mean[rr]) * rstd[rr] * gc + bc;
            xout[(size_t)(brow + rowb + rr) * CE + col] = x;
            if (DO_FFN) A_s[rowb + rr][col] = f2bf(x);
        }
    }

    if (DO_FFN) {
        // ---- GEMM2: x@WT2 + bias2, relu -> Hout bf16 ----
        f32x4 acc2[4] = {};
        for (int kc = 0; kc < 4; ++kc) {
            int k0 = kc * 64;
            __syncthreads();
            {
                int n = tid >> 1, half = (tid & 1) * 32;
                const unsigned short* bp = WT2 + (size_t)n * CE + k0 + half;
#pragma unroll
                for (int q = 0; q < 4; ++q)
                    *reinterpret_cast<u16x8*>(&Bs[n][half + q * 8]) = *reinterpret_cast<const u16x8*>(bp + q * 8);
                if (kc == 0 && tid < 256) bias_s[tid] = bias2[tid];
            }
            __syncthreads();
#pragma unroll
            for (int sub = 0; sub < 2; ++sub) {
                bf16x8 a = *reinterpret_cast<const bf16x8*>(&A_s[wr * 16 + lo][k0 + sub * 32 + hi * 8]);
#pragma unroll
                for (int nt = 0; nt < 4; ++nt) {
                    bf16x8 b = *reinterpret_cast<const bf16x8*>(&Bs[wc * 64 + nt * 16 + lo][sub * 32 + hi * 8]);
                    acc2[nt] = __builtin_amdgcn_mfma_f32_16x16x32_bf16(a, b, acc2[nt], 0, 0, 0);
                }
            }
        }
#pragma unroll
        for (int nt = 0; nt < 4; ++nt) {
            int col = wc * 64 + nt * 16 + lo;
            float bc = bias_s[col];
#pragma unroll
            for (int rr = 0; rr < 4; ++rr) {
                float hv = fmaxf(acc2[nt][rr] + bc, 0.f);
                Hout[(size_t)(brow + rowb + rr) * CE + col] = f2bf(hv);
            }
        }
    }
}

// ---------------------------------------------------------------- attention
// Persistent-KV bf16 MFMA flash.  Q,V,Ctx all bf16 [B*S][E].  K == Q (kq_same).
// Grid: (b,h,half) = 256 blocks x 512 threads (8 waves). Stage all 512 keys
// once; each wave computes 2 query-groups with no block barriers in the loop.
// Router head-mask applied at ctx writeout. strict row 0 -> uniform (s=0).
__global__ __launch_bounds__(512) void attn_mfma(
    const unsigned short* __restrict__ Q, const unsigned short* __restrict__ V,
    unsigned short* __restrict__ Ctx, const unsigned char* __restrict__ gm,
    int strict)
{
    __shared__ __attribute__((aligned(16))) unsigned short Ks[512][40];     // 40 KB
    __shared__ __attribute__((aligned(16))) unsigned short VTc[8][32][72];  // 36 KB
    __shared__ __attribute__((aligned(16))) unsigned short Ps[8][16][72];   // 18 KB (also f32 ctxbuf[16][36])

    int blk = blockIdx.x;
    int half = blk & 1;
    int h = (blk >> 1) & 7;
    int b = blk >> 4;
    int tid = threadIdx.x;
    int w = tid >> 6, lane = tid & 63;
    int lo = lane & 15, hi = lane >> 4;

    // ---- stage all of K (=Q) and V^T (once) ----
#pragma unroll
    for (int r = 0; r < 4; ++r) {
        int row = (tid >> 2) + r * 128;
        int d0 = (tid & 3) * 8;
        u16x8 kv = *reinterpret_cast<const u16x8*>(Q + ((size_t)b * CS + row) * CE + h * 32 + d0);
        *reinterpret_cast<u16x8*>(&Ks[row][d0]) = kv;
        u16x8 vv = *reinterpret_cast<const u16x8*>(V + ((size_t)b * CS + row) * CE + h * 32 + d0);
        int c8 = row >> 6, kc = row & 63;
        VTc[c8][d0+0][kc]=vv[0]; VTc[c8][d0+1][kc]=vv[1];
        VTc[c8][d0+2][kc]=vv[2]; VTc[c8][d0+3][kc]=vv[3];
        VTc[c8][d0+4][kc]=vv[4]; VTc[c8][d0+5][kc]=vv[5];
        VTc[c8][d0+6][kc]=vv[6]; VTc[c8][d0+7][kc]=vv[7];
    }
    __syncthreads();

    for (int it = 0; it < 2; ++it) {
        int gg = half * 16 + w + it * 8;     // global query group 0..31
        int qg0 = gg * 16;
        int qg = qg0 + lo;                   // this lane's query row
        bool uni = strict && (qg == 0);
        bf16x8 qfrag = *reinterpret_cast<const bf16x8*>(&Ks[qg0 + lo][hi * 8]);

        f32x4 ctx0 = {0.f,0.f,0.f,0.f}, ctx1 = {0.f,0.f,0.f,0.f};
        float m = -1e30f, l = 0.f;
        int nch = (strict && qg0 == 0) ? 8 : ((gg >> 2) + 1);

        for (int c = 0; c < nch; ++c) {
            f32x4 sacc[4];
#pragma unroll
            for (int kt = 0; kt < 4; ++kt) {
                bf16x8 kfrag = *reinterpret_cast<const bf16x8*>(&Ks[c * 64 + kt * 16 + lo][hi * 8]);
                f32x4 z = {0.f,0.f,0.f,0.f};
                sacc[kt] = __builtin_amdgcn_mfma_f32_16x16x32_bf16(kfrag, qfrag, z, 0, 0, 0);
            }
            float sv[16];
            float mt = -1e30f;
#pragma unroll
            for (int kt = 0; kt < 4; ++kt)
#pragma unroll
                for (int r = 0; r < 4; ++r) {
                    int kidx = c * 64 + kt * 16 + hi * 4 + r;
                    float s = sacc[kt][r] * SCALE;
                    bool valid = strict ? (kidx < qg) : (kidx <= qg);
                    s = valid ? s : -1e30f;
                    if (uni) s = 0.f;
                    sv[kt * 4 + r] = s;
                    mt = fmaxf(mt, s);
                }
            mt = fmaxf(mt, __shfl_xor(mt, 16));
            mt = fmaxf(mt, __shfl_xor(mt, 32));
            float mn = fmaxf(m, mt);
            float co = __expf(m - mn);
            float lt = 0.f;
#pragma unroll
            for (int i = 0; i < 16; ++i) {
                float p = __expf(sv[i] - mn);
                sv[i] = p;
                lt += p;
            }
            lt += __shfl_xor(lt, 16);
            lt += __shfl_xor(lt, 32);
            l = l * co + lt;
            m = mn;
#pragma unroll
            for (int r = 0; r < 4; ++r) { ctx0[r] *= co; ctx1[r] *= co; }
#pragma unroll
            for (int kt = 0; kt < 4; ++kt) {
                unsigned short* pd = &Ps[w][lo][kt * 16 + hi * 4];
                pd[0] = f2bf(sv[kt * 4 + 0]); pd[1] = f2bf(sv[kt * 4 + 1]);
                pd[2] = f2bf(sv[kt * 4 + 2]); pd[3] = f2bf(sv[kt * 4 + 3]);
            }
            // wave-local ordering: P writes (cross-lane) -> P reads
            asm volatile("s_waitcnt lgkmcnt(0)" ::: "memory");
            __builtin_amdgcn_sched_barrier(0);
#pragma unroll
            for (int kh = 0; kh < 2; ++kh) {
                bf16x8 pfrag = *reinterpret_cast<const bf16x8*>(&Ps[w][lo][kh * 32 + hi * 8]);
                bf16x8 v0 = *reinterpret_cast<const bf16x8*>(&VTc[c][lo][kh * 32 + hi * 8]);
                bf16x8 v1 = *reinterpret_cast<const bf16x8*>(&VTc[c][16 + lo][kh * 32 + hi * 8]);
                ctx0 = __builtin_amdgcn_mfma_f32_16x16x32_bf16(v0, pfrag, ctx0, 0, 0, 0);
                ctx1 = __builtin_amdgcn_mfma_f32_16x16x32_bf16(v1, pfrag, ctx1, 0, 0, 0);
            }
        }

        // ---- normalize + writeout (mask applied) via per-wave LDS transpose ----
        float inv = 1.f / l;
        float* cb = reinterpret_cast<float*>(&Ps[w][0][0]);   // [16 q][36 d]
#pragma unroll
        for (int r = 0; r < 4; ++r) {
            cb[lo * 36 + (hi * 4 + r)]      = ctx0[r] * inv;
            cb[lo * 36 + (16 + hi * 4 + r)] = ctx1[r] * inv;
        }
        asm volatile("s_waitcnt lgkmcnt(0)" ::: "memory");
        __builtin_amdgcn_sched_barrier(0);
        {
            int qloc = lane >> 2, d0 = (lane & 3) * 8;
            const float* src = cb + qloc * 36 + d0;
            int i = qg0 + qloc;
            float mf = ((gm[(size_t)b * CS + i] >> h) & 1) ? 1.f : 0.f;
            u16x8 o;
#pragma unroll
            for (int k = 0; k < 8; ++k) o[k] = f2bf(src[k] * mf);
            *reinterpret_cast<u16x8*>(Ctx + ((size_t)b * CS + i) * CE + h * 32 + d0) = o;
        }
        asm volatile("s_waitcnt lgkmcnt(0)" ::: "memory");   // cb reads done before next it's P writes
        __builtin_amdgcn_sched_barrier(0);
    }
}

// ---------------------------------------------------------------- router gate mask
// Wave per token (8 waves/block): logits = q_in @ Wg; top-4 -> 8-bit head mask.
__global__ __launch_bounds__(512) void gate_mask(
    const float* __restrict__ qin, const float* __restrict__ Wg,
    unsigned char* __restrict__ mb)
{
    int w = threadIdx.x >> 6, lane = threadIdx.x & 63;
    int t = blockIdx.x * 8 + w;
    const float* q = qin + (size_t)t * CE;
    float p[CNDYN] = {};
#pragma unroll
    for (int r = 0; r < 4; ++r) {
        int e = lane + r * 64;
        float qe = q[e];
        const float* wg = &Wg[(size_t)e * CNDYN];
#pragma unroll
        for (int j = 0; j < CNDYN; ++j) p[j] += qe * wg[j];
    }
#pragma unroll
    for (int o = 32; o > 0; o >>= 1)
#pragma unroll
        for (int j = 0; j < CNDYN; ++j) p[j] += __shfl_down(p[j], o);
    if (lane == 0) {
        int mask = 3;
        for (int j = 0; j < CNDYN; ++j) {
            int rank = 0;
            for (int k = 0; k < CNDYN; ++k)
                if (p[k] > p[j] || (p[k] == p[j] && k < j)) rank++;
            if (rank < 4) mask |= 1 << (2 + j);
        }
        mb[t] = (unsigned char)mask;
    }
}

// ---------------------------------------------------------------- concat (bf16 out)
__global__ __launch_bounds__(256) void concat_kernel(
    const float* __restrict__ x, const float* __restrict__ qe,
    unsigned short* __restrict__ cat)
{
    int t = blockIdx.x, e = threadIdx.x;
    int o = e * 2;
    float2 v;
    if (o < 256) v = *reinterpret_cast<const float2*>(&x[(size_t)t * CE + o]);
    else         v = *reinterpret_cast<const float2*>(&qe[(size_t)t * CE + o - 256]);
    unsigned pk = (unsigned)f2bf(v.x) | ((unsigned)f2bf(v.y) << 16);
    *reinterpret_cast<unsigned*>(&cat[(size_t)t * 512 + o]) = pk;
}

// ---------------------------------------------------------------- final dot + sigmoid
__global__ __launch_bounds__(64) void final_kernel(
    const float* __restrict__ H2, const float* __restrict__ W3,
    const float* __restrict__ b3, float* __restrict__ out)
{
    int t = blockIdx.x, lane = threadIdx.x;
    const float* h = H2 + (size_t)t * CE;
    float s = 0.f;
#pragma unroll
    for (int r = 0; r < 4; ++r) {
        int e = lane + r * 64;
        s += h[e] * W3[e];
    }
#pragma unroll
    for (int o = 32; o > 0; o >>= 1) s += __shfl_down(s, o);
    if (lane == 0) {
        float v = 1.f / (1.f + __expf(-(s + b3[0])));
        int b = t >> 9, si = t & 511;
        if (si > 0) out[(size_t)b * (CS - 1) + si - 1] = v;
    }
}

// ---------------------------------------------------------------- driver
extern "C" void kernel_launch(void* const* d_in, const int* in_sizes, int n_in,
                              void* d_out, int out_size, void* d_ws, size_t ws_size,
                              hipStream_t stream)
{
    const int* skills    = (const int*)d_in[0];
    const int* responses = (const int*)d_in[1];
    const int* questions = (const int*)d_in[2];
    const float* q_embed       = (const float*)d_in[4];
    const float* qa_embed      = (const float*)d_in[5];
    const float* q_embed_diff  = (const float*)d_in[6];
    const float* qa_embed_diff = (const float*)d_in[7];
    const float* difficult     = (const float*)d_in[8];
    const float* Wq = (const float*)d_in[9];  const float* bq = (const float*)d_in[10];
    const float* Wv = (const float*)d_in[11]; const float* bv = (const float*)d_in[12];
    const float* Wo = (const float*)d_in[13]; const float* bo = (const float*)d_in[14];
    const float* Wg = (const float*)d_in[15];
    const float* ln1g = (const float*)d_in[16]; const float* ln1b = (const float*)d_in[17];
    const float* ln2g = (const float*)d_in[18]; const float* ln2b = (const float*)d_in[19];
    const float* fW1 = (const float*)d_in[20]; const float* fb1 = (const float*)d_in[21];
    const float* fW2 = (const float*)d_in[22]; const float* fb2 = (const float*)d_in[23];
    const float* oW1 = (const float*)d_in[24]; const float* ob1 = (const float*)d_in[25];
    const float* oW2 = (const float*)d_in[26]; const float* ob2 = (const float*)d_in[27];
    const float* oW3 = (const float*)d_in[28]; const float* ob3 = (const float*)d_in[29];
    float* out = (float*)d_out;

    char* ws = (char*)d_ws;
    const size_t R = (size_t)CT * CE * sizeof(float);   // 8 MB per region
    float* q_emb = (float*)(ws + 0 * R);
    float* xb    = (float*)(ws + 1 * R);                // also final H2 (f32)
    float* yb    = (float*)(ws + 2 * R);
    float* S0f   = (float*)(ws + 3 * R);                // bf16 Q / bf16 H / bf16 cat
    float* S1f   = (float*)(ws + 4 * R);                // bf16 V
    float* S2f   = (float*)(ws + 5 * R);                // bf16 ctx / bf16 H1(MLP)
    float* x1buf = (float*)(ws + 6 * R);                // f32 x1 (post-LN1 residual)
    unsigned short* S0b = (unsigned short*)S0f;
    unsigned short* S1b = (unsigned short*)S1f;
    unsigned short* S2b = (unsigned short*)S2f;
    unsigned short* qvT = (unsigned short*)(ws + 7 * R);  // [12][512][256]
    unsigned short* woT = qvT + (size_t)12 * 131072;      // [12][256][256]
    unsigned short* w1T = woT + (size_t)12 * 65536;
    unsigned short* w2T = w1T + (size_t)12 * 65536;
    unsigned short* o1T = w2T + (size_t)12 * 65536;       // [512][512]
    unsigned short* o2T = o1T + (size_t)512 * 512;        // [256][512]
    unsigned char* maskbuf = (unsigned char*)(o2T + (size_t)256 * 512);
    (void)in_sizes; (void)n_in; (void)out_size; (void)ws_size;

    // weight conversion (every call; graph-safe)
    prep_w_layers<<<dim3(4, 4, 60), 256, 0, stream>>>(Wq, Wv, Wo, fW1, fW2, qvT, woT, w1T, w2T);
    prep_w_one<<<dim3(8, 8), 256, 0, stream>>>(oW1, o1T, 512, 512);
    prep_w_one<<<dim3(4, 8), 256, 0, stream>>>(oW2, o2T, 512, 256);

    embed_kernel<<<CT, 256, 0, stream>>>(skills, responses, questions,
        q_embed, qa_embed, q_embed_diff, qa_embed_diff, difficult, q_emb, yb, xb);

    auto layer = [&](int li, const float* qin, const float* vin, float* outc, int strict) {
        if (qin == vin) {   // fused Q+V projection (N=512, split at 256) -> bf16
            gemm_mfma<float, unsigned short><<<dim3(8, 128), 256, 0, stream>>>(
                qin, qvT + (size_t)li * 131072, bq + (size_t)li * CE, S0b,
                bv + (size_t)li * CE, S1b, CT, 512, CE, 0, 256);
        } else {
            gemm_mfma<float, unsigned short><<<dim3(4, 128), 256, 0, stream>>>(
                qin, qvT + (size_t)li * 131072, bq + (size_t)li * CE, S0b,
                nullptr, nullptr, CT, CE, CE, 0, 0);
            gemm_mfma<float, unsigned short><<<dim3(4, 128), 256, 0, stream>>>(
                vin, qvT + (size_t)li * 131072 + 65536, bv + (size_t)li * CE, S1b,
                nullptr, nullptr, CT, CE, CE, 0, 0);
        }
        gate_mask<<<CT / 8, 512, 0, stream>>>(qin, Wg + (size_t)li * CE * CNDYN, maskbuf);
        attn_mfma<<<CB * CH * 2, 512, 0, stream>>>(S0b, S1b, S2b, maskbuf, strict);
        // ctx@Wo+bo -> +qin -> LN1 -> x1 (f32) ; x1@W1+b1 relu -> H (bf16, S0b)
        fused_tail<1><<<CT / 32, 512, 0, stream>>>(
            S2b, woT + (size_t)li * 65536, bo + (size_t)li * CE, qin,
            ln1g + (size_t)li * CE, ln1b + (size_t)li * CE, x1buf,
            w1T + (size_t)li * 65536, fb1 + (size_t)li * CE, S0b);
        // H@W2+b2 -> +x1 -> LN2 -> outc (f32)
        fused_tail<0><<<CT / 32, 512, 0, stream>>>(
            S0b, w2T + (size_t)li * 65536, fb2 + (size_t)li * CE, x1buf,
            ln2g + (size_t)li * CE, ln2b + (size_t)li * CE, outc,
            nullptr, nullptr, nullptr);
    };

    for (int i = 0; i < 4; ++i) layer(i, yb, yb, yb, 0);
    int li = 4;
    for (int r = 0; r < 4; ++r) {
        layer(li, xb, xb, xb, 0); li++;
        layer(li, xb, yb, xb, 1); li++;   // q=x, k=x, v=y, strict mask
    }

    // output MLP: cat(bf16) -> H1(bf16, relu) -> H2(f32, relu) -> sigmoid dot
    concat_kernel<<<CT, 256, 0, stream>>>(xb, q_emb, S0b);
    gemm_mfma<unsigned short, unsigned short><<<dim3(8, 128), 256, 0, stream>>>(
        S0b, o1T, ob1, S2b, nullptr, nullptr, CT, 512, 512, 1, 0);
    gemm_mfma<unsigned short, float><<<dim3(4, 128), 256, 0, stream>>>(
        S2b, o2T, ob2, xb, nullptr, nullptr, CT, 256, 512, 1, 0);
    final_kernel<<<CT, 64, 0, stream>>>(xb, oW3, ob3, out);
}